// Round 2
// baseline (89.632 us; speedup 1.0000x reference)
//
#include <hip/hip_runtime.h>
#include <math.h>

#define BATCH 512
#define CCH   64
#define NND   32
#define VOC   100
#define DEMB  32
#define HID   64
#define NEDGE 256
#define NT    37

// ws word layout:
// [0..63]     offs   (NND+1 = 33 used)     ints
// [64..383]   srcs   (NEDGE+NND = 288)     ints
// [384..703]  norms  (288)                 floats
// [704..767]  pc     (NT+1 = 38)           floats  (prefix sums of softmax(att))
// [768..831]  pt     (38)                  floats  (suffix sums)

__global__ void a3_setup_kernel(const int* __restrict__ tei,
                                const float* __restrict__ att,
                                int* __restrict__ ws_i,
                                float* __restrict__ ws_f) {
    if (threadIdx.x != 0) return;
    int*   offs  = ws_i;
    int*   srcs  = ws_i + 64;
    float* norms = ws_f + 384;
    float* pc    = ws_f + 704;
    float* pt    = ws_f + 768;

    const int* src = tei;
    const int* dst = tei + NEDGE;

    int deg[NND];
    for (int n = 0; n < NND; ++n) deg[n] = 0;
    for (int e = 0; e < NEDGE; ++e) deg[dst[e]]++;
    for (int n = 0; n < NND; ++n) deg[n]++;            // self loops
    float dinv[NND];
    for (int n = 0; n < NND; ++n) dinv[n] = 1.0f / sqrtf((float)deg[n]);

    offs[0] = 0;
    for (int n = 0; n < NND; ++n) offs[n + 1] = offs[n] + deg[n];
    int cur[NND];
    for (int n = 0; n < NND; ++n) cur[n] = offs[n];
    for (int e = 0; e < NEDGE; ++e) {
        int d = dst[e], s = src[e];
        int p = cur[d]++;
        srcs[p]  = s;
        norms[p] = dinv[s] * dinv[d];
    }
    for (int n = 0; n < NND; ++n) {
        int p = cur[n]++;
        srcs[p]  = n;
        norms[p] = dinv[n] * dinv[n];
    }

    // softmax(att) prefix/suffix sums
    float m = att[0];
    for (int t = 1; t < NT; ++t) m = fmaxf(m, att[t]);
    float p[NT];
    float s = 0.f;
    for (int t = 0; t < NT; ++t) { p[t] = expf(att[t] - m); s += p[t]; }
    float inv = 1.0f / s;
    float run = 0.f;
    for (int l = 0; l <= NT; ++l) { pc[l] = run * inv; if (l < NT) run += p[l]; }
    float run2 = 0.f;
    for (int l = NT; l >= 0; --l) { pt[l] = run2 * inv; if (l > 0) run2 += p[l - 1]; }
}

__global__ __launch_bounds__(256, 2)
void a3tgcn_main_kernel(const int* __restrict__ x_batch,
                        const int* __restrict__ LOSb,
                        const float* __restrict__ emb,
                        const float* __restrict__ Wz, const float* __restrict__ bz,
                        const float* __restrict__ Wh, const float* __restrict__ bh,
                        const float* __restrict__ Lz, const float* __restrict__ lbz,
                        const float* __restrict__ Lh, const float* __restrict__ lbh,
                        const float* __restrict__ Wc1, const float* __restrict__ bc1,
                        const float* __restrict__ Wc2, const float* __restrict__ bc2,
                        const int* __restrict__ ws_i, const float* __restrict__ ws_f,
                        float* __restrict__ out) {
    __shared__ int   xb[CCH];
    __shared__ float xe[CCH][DEMB];     // gathered embeddings: rows 0..31 ad, 32..63 dis
    __shared__ float xwz[NND][HID];
    __shared__ float xwh[NND][HID];
    __shared__ float aggz[NND][HID];
    __shared__ float aggh[NND][HID];
    __shared__ float hacc[NND][HID];
    __shared__ float pooled[HID];
    __shared__ float h1s[2 * HID];
    __shared__ int   soffs[NND + 1];
    __shared__ int   ssrcs[NEDGE + NND];
    __shared__ float snorm[NEDGE + NND];

    const int b   = blockIdx.x;
    const int tid = threadIdx.x;
    const int hd  = tid & 63;
    const int n0  = tid >> 6;          // wave-uniform: 0..3

    // stage per-batch indices + CSR into LDS
    if (tid < CCH) xb[tid] = x_batch[b * CCH + tid];
    if (tid <= NND) soffs[tid] = ws_i[tid];
    ssrcs[tid] = ws_i[64 + tid];
    snorm[tid] = ws_f[384 + tid];
    if (tid < NND) { ssrcs[256 + tid] = ws_i[64 + 256 + tid]; snorm[256 + tid] = ws_f[384 + 256 + tid]; }
    __syncthreads();

    // gather embeddings: 2048 elements, 8 per thread, coalesced rows
#pragma unroll
    for (int i = 0; i < 8; ++i) {
        int el = tid + 256 * i;
        int c = el >> 5, k = el & 31;
        xe[c][k] = emb[(c * VOC + xb[c]) * DEMB + k];
    }

    const int   los = LOSb[b];
    const float cA  = ws_f[704 + los];   // sum of probs for t <  LOS  (ad weight)
    const float cD  = ws_f[768 + los];   // sum of probs for t >= LOS  (dis weight)
    __syncthreads();

    for (int v = 0; v < 2; ++v) {
        // ---- xw = x_v @ W  (z and h gates) ----
        float az[8], ah[8];
#pragma unroll
        for (int j = 0; j < 8; ++j) { az[j] = 0.f; ah[j] = 0.f; }
        for (int e = 0; e < DEMB; ++e) {
            float wz = Wz[e * HID + hd];
            float wh = Wh[e * HID + hd];
#pragma unroll
            for (int j = 0; j < 8; ++j) {
                float x = xe[v * NND + n0 + 4 * j][e];   // wave-uniform -> LDS broadcast
                az[j] = fmaf(x, wz, az[j]);
                ah[j] = fmaf(x, wh, ah[j]);
            }
        }
#pragma unroll
        for (int j = 0; j < 8; ++j) {
            xwz[n0 + 4 * j][hd] = az[j];
            xwh[n0 + 4 * j][hd] = ah[j];
        }
        __syncthreads();

        // ---- GCN aggregation over CSR (incl. self loops), + bias ----
#pragma unroll
        for (int j = 0; j < 8; ++j) {
            int n = n0 + 4 * j;
            float sz = bz[hd], sh = bh[hd];
            int beg = soffs[n], end = soffs[n + 1];
            for (int q = beg; q < end; ++q) {
                int s = ssrcs[q];
                float w = snorm[q];
                sz = fmaf(w, xwz[s][hd], sz);
                sh = fmaf(w, xwh[s][hd], sh);
            }
            aggz[n][hd] = sz;
            aggh[n][hd] = sh;
        }
        __syncthreads();

        // ---- @ L[:HID] + bias, gates, weighted accumulate ----
        float zz[8], hh[8];
#pragma unroll
        for (int j = 0; j < 8; ++j) { zz[j] = 0.f; hh[j] = 0.f; }
        for (int k = 0; k < HID; ++k) {
            float lz = Lz[k * HID + hd];
            float lh = Lh[k * HID + hd];
#pragma unroll
            for (int j = 0; j < 8; ++j) {
                int n = n0 + 4 * j;
                zz[j] = fmaf(aggz[n][k], lz, zz[j]);
                hh[j] = fmaf(aggh[n][k], lh, hh[j]);
            }
        }
        const float cv = (v == 0) ? cA : cD;
#pragma unroll
        for (int j = 0; j < 8; ++j) {
            int n = n0 + 4 * j;
            float zlin = zz[j] + lbz[hd];
            float hlin = hh[j] + lbh[hd];
            float Zs = 1.0f / (1.0f + expf(-zlin));
            float Ht = tanhf(hlin);
            float cell = (1.0f - Zs) * Ht;
            if (v == 0) hacc[n][hd] = cv * cell;
            else        hacc[n][hd] += cv * cell;
        }
        __syncthreads();
    }

    // ---- mean over nodes ----
    if (tid < HID) {
        float s = 0.f;
#pragma unroll
        for (int n = 0; n < NND; ++n) s += hacc[n][tid];
        pooled[tid] = s * (1.0f / 32.0f);
    }
    __syncthreads();

    // ---- relu(pooled @ Wc1 + bc1) * Wc2 (elementwise partials) ----
    if (tid < 2 * HID) {
        float a = bc1[tid];
        for (int k = 0; k < HID; ++k) a = fmaf(pooled[k], Wc1[k * 2 * HID + tid], a);
        float r = fmaxf(a, 0.f);
        h1s[tid] = r * Wc2[tid];
    }
    __syncthreads();

    if (tid == 0) {
        float s = bc2[0];
#pragma unroll
        for (int j = 0; j < 2 * HID; ++j) s += h1s[j];
        out[b] = s;
    }
}

extern "C" void kernel_launch(void* const* d_in, const int* in_sizes, int n_in,
                              void* d_out, int out_size, void* d_ws, size_t ws_size,
                              hipStream_t stream) {
    const int*   x_batch = (const int*)d_in[0];
    const int*   LOSb    = (const int*)d_in[1];
    const int*   tei     = (const int*)d_in[2];
    const float* emb     = (const float*)d_in[3];
    const float* Wz      = (const float*)d_in[4];
    const float* bz      = (const float*)d_in[5];
    const float* Wh      = (const float*)d_in[8];
    const float* bh      = (const float*)d_in[9];
    const float* Lz      = (const float*)d_in[10];
    const float* lbz     = (const float*)d_in[11];
    const float* Lh      = (const float*)d_in[14];
    const float* lbh     = (const float*)d_in[15];
    const float* att     = (const float*)d_in[16];
    const float* Wc1     = (const float*)d_in[17];
    const float* bc1     = (const float*)d_in[18];
    const float* Wc2     = (const float*)d_in[19];
    const float* bc2     = (const float*)d_in[20];
    int*   ws_i = (int*)d_ws;
    float* ws_f = (float*)d_ws;
    float* outp = (float*)d_out;

    hipLaunchKernelGGL(a3_setup_kernel, dim3(1), dim3(64), 0, stream, tei, att, ws_i, ws_f);
    hipLaunchKernelGGL(a3tgcn_main_kernel, dim3(BATCH), dim3(256), 0, stream,
                       x_batch, LOSb, emb, Wz, bz, Wh, bh, Lz, lbz, Lh, lbh,
                       Wc1, bc1, Wc2, bc2, ws_i, ws_f, outp);
}